// Round 16
// baseline (337.877 us; speedup 1.0000x reference)
//
#include <hip/hip_runtime.h>

#define F_IN 128
#define HID 16
#define HEADS 12
#define HF (HEADS*HID)   // 192
#define OUT_C 32

typedef _Float16 f16;

// ---------------- convert + per-block inline dtype detection ----------------
// Every block redundantly samples the same 2048 odd int32 words (L2-hot) and
// OR-reduces: int64 data (values < 2^31) has all high words == 0.
__global__ void k_convert(const void* __restrict__ ei, int E,
                          int* __restrict__ src32, int* __restrict__ dst32,
                          int* __restrict__ count) {
    __shared__ int sdet[256];
    int t = threadIdx.x;
    const int* w32 = (const int*)ei;
    long long half = (long long)E;
    int a = 0;
    #pragma unroll
    for (int i = 0; i < 8; i++) {
        long long k = ((long long)(t + i * 256) * half) / 2048;
        a |= w32[2 * k + 1];
    }
    sdet[t] = a;
    __syncthreads();
    for (int off = 128; off >= 1; off >>= 1) {
        if (t < off) sdet[t] |= sdet[t + off];
        __syncthreads();
    }
    int is32 = sdet[0];                      // !=0 => int32 layout
    int e = blockIdx.x * blockDim.x + t;
    if (e >= E) return;
    int s, d;
    if (!is32) {
        const long long* p = (const long long*)ei;
        s = (int)p[e];
        d = (int)p[(size_t)E + e];
    } else {
        s = w32[e];
        d = w32[(size_t)E + e];
    }
    src32[e] = s;
    dst32[e] = d;
    atomicAdd(&count[d], 1);
}

// ---------------- CSR scan ----------------
__global__ void k_scan(const int* __restrict__ count, int* __restrict__ rowstart,
                       float* __restrict__ dinv, int n) {
    __shared__ int part[1024];
    int t = threadIdx.x;
    int chunk = (n + 1023) >> 10;
    int beg = t * chunk;
    int end = beg + chunk; if (end > n) end = n;
    int s = 0;
    for (int i = beg; i < end; i++) s += count[i];
    part[t] = s;
    __syncthreads();
    for (int off = 1; off < 1024; off <<= 1) {
        int v = (t >= off) ? part[t - off] : 0;
        __syncthreads();
        part[t] += v;
        __syncthreads();
    }
    int run = (t == 0) ? 0 : part[t - 1];
    for (int i = beg; i < end; i++) {
        rowstart[i] = run;
        int c = count[i];
        run += c;
        dinv[i] = rsqrtf((float)(c + 1));   // +1 self loop
    }
    if (t == 1023) rowstart[n] = run;
}

// ---------------- fused CSR-fill + GEMM1 (independent work, one dispatch) ----------------
// blocks [0,eb): fill csr. blocks [eb, eb+nb16): h1 = x @ W1 -> fp16.
__global__ void k_fill_gemm1(const int* __restrict__ src32, const int* __restrict__ dst32,
                             int E, const int* __restrict__ rowstart, int* __restrict__ cursor,
                             int* __restrict__ csr, const float* __restrict__ x,
                             const float* __restrict__ W1, f16* __restrict__ h1,
                             int n, int eb) {
    __shared__ float sW[F_IN * HID];
    __shared__ float sX[16][F_IN + 1];
    int b = blockIdx.x;
    if (b < eb) {                            // block-uniform branch, no syncthreads inside
        int e = b * 256 + threadIdx.x;
        if (e < E) {
            int d = dst32[e];
            int p = atomicAdd(&cursor[d], 1);
            csr[rowstart[d] + p] = src32[e];
        }
        return;
    }
    int t = threadIdx.x;
    for (int i = t; i < F_IN * HID; i += 256) sW[i] = W1[i];
    int node0 = (b - eb) * 16;
    for (int i = t; i < 16 * F_IN; i += 256) {
        int r = i >> 7, c = i & 127;
        int node = node0 + r;
        sX[r][c] = (node < n) ? x[node * F_IN + c] : 0.f;
    }
    __syncthreads();
    int ln = t >> 4, c = t & 15;
    float acc = 0.f;
    #pragma unroll 8
    for (int k = 0; k < F_IN; k++) acc += sX[ln][k] * sW[k * HID + c];
    int node = node0 + ln;
    if (node < n) h1[node * HID + c] = (f16)acc;
}

// hg = x1(N,16) @ Wg(16,192) + fused attention dots. Persistent, register weights.
__global__ void k_gemm_gat(const float* __restrict__ x1, const float* __restrict__ Wg,
                           const float* __restrict__ att_s, const float* __restrict__ att_d,
                           f16* __restrict__ hg, float* __restrict__ a_s,
                           float* __restrict__ a_d, int n) {
    int c = threadIdx.x;          // 0..191 output column
    int lane = c & 63;
    int hh = c >> 4, ci = c & 15;
    float ats = att_s[c];
    float atd = att_d[c];
    float wcol[HID];
    #pragma unroll
    for (int k = 0; k < HID; k++) wcol[k] = Wg[k * HF + c];
    for (int node = blockIdx.x; node < n; node += gridDim.x) {
        float xv = x1[node * HID + (lane & 15)];
        float acc = 0.f;
        #pragma unroll
        for (int k = 0; k < HID; k++) acc += __shfl(xv, k) * wcol[k];
        hg[(size_t)node * HF + c] = (f16)acc;
        float vs = acc * ats, vd = acc * atd;
        #pragma unroll
        for (int msk = 8; msk >= 1; msk >>= 1) {
            vs += __shfl_xor(vs, msk);
            vd += __shfl_xor(vd, msk);
        }
        if (ci == 0) {
            a_s[node * HEADS + hh] = vs;
            a_d[node * HEADS + hh] = vd;
        }
    }
}

// ---------------- Aggregation kernels ----------------

// GCN aggregate: one WAVE per node; 16 cols x 4 edge slots. csr row wave-preloaded;
// shfl at FULL EXEC (hoisted), loads predicated -> no inactive-lane-shfl UB.
// 16 gathers in flight.
__global__ void k_gcn_agg(const f16* __restrict__ h, const int* __restrict__ rowstart,
                          const int* __restrict__ csr, const float* __restrict__ dinv,
                          const float* __restrict__ bias, const float* __restrict__ resid,
                          float* __restrict__ out, int n) {
    int node = (blockIdx.x * blockDim.x + threadIdx.x) >> 6;
    int lane = threadIdx.x & 63;
    if (node >= n) return;
    int c = lane & 15, jj = lane >> 4;
    float dn = dinv[node];
    int base = rowstart[node], deg = rowstart[node + 1] - base;
    int dcap = deg < 64 ? deg : 64;
    int eidx = (lane < dcap) ? csr[base + lane] : 0;
    float acc = (jj == 0) ? (float)h[node * HID + c] * dn : 0.f;   // self loop
    for (int j = 0; j < dcap; j += 16) {     // wave-uniform trip count
        int i0 = j + jj, i1 = i0 + 4, i2 = i0 + 8, i3 = i0 + 12;
        int s0 = __shfl(eidx, i0);           // full exec
        int s1 = __shfl(eidx, i1);
        int s2 = __shfl(eidx, i2);
        int s3 = __shfl(eidx, i3);
        if (i0 < dcap) acc += (float)h[s0 * HID + c] * dinv[s0];
        if (i1 < dcap) acc += (float)h[s1 * HID + c] * dinv[s1];
        if (i2 < dcap) acc += (float)h[s2 * HID + c] * dinv[s2];
        if (i3 < dcap) acc += (float)h[s3 * HID + c] * dinv[s3];
    }
    for (int j = 64 + jj; j < deg; j += 4) { // deg>64 fallback (≈never)
        int s0 = csr[base + j];
        acc += (float)h[s0 * HID + c] * dinv[s0];
    }
    acc += __shfl_xor(acc, 16);
    acc += __shfl_xor(acc, 32);
    if (lane < 16) {
        float v = fmaxf(acc * dn + bias[c], 0.f);
        if (resid) v += resid[node * HID + c];
        out[node * HID + c] = v;
    }
}

// GCN aggregate layer-2 + fused GEMM3 epilogue (same preload pattern).
__global__ void k_gcn_agg_f3(const f16* __restrict__ h, const int* __restrict__ rowstart,
                             const int* __restrict__ csr, const float* __restrict__ dinv,
                             const float* __restrict__ bias, const float* __restrict__ W3,
                             float* __restrict__ x3o, f16* __restrict__ h3o, int n) {
    int node = (blockIdx.x * blockDim.x + threadIdx.x) >> 6;
    int lane = threadIdx.x & 63;
    if (node >= n) return;
    int c = lane & 15, jj = lane >> 4;
    float dn = dinv[node];
    int base = rowstart[node], deg = rowstart[node + 1] - base;
    int dcap = deg < 64 ? deg : 64;
    int eidx = (lane < dcap) ? csr[base + lane] : 0;
    float acc = (jj == 0) ? (float)h[node * HID + c] * dn : 0.f;
    for (int j = 0; j < dcap; j += 16) {
        int i0 = j + jj, i1 = i0 + 4, i2 = i0 + 8, i3 = i0 + 12;
        int s0 = __shfl(eidx, i0);
        int s1 = __shfl(eidx, i1);
        int s2 = __shfl(eidx, i2);
        int s3 = __shfl(eidx, i3);
        if (i0 < dcap) acc += (float)h[s0 * HID + c] * dinv[s0];
        if (i1 < dcap) acc += (float)h[s1 * HID + c] * dinv[s1];
        if (i2 < dcap) acc += (float)h[s2 * HID + c] * dinv[s2];
        if (i3 < dcap) acc += (float)h[s3 * HID + c] * dinv[s3];
    }
    for (int j = 64 + jj; j < deg; j += 4) {
        int s0 = csr[base + j];
        acc += (float)h[s0 * HID + c] * dinv[s0];
    }
    acc += __shfl_xor(acc, 16);
    acc += __shfl_xor(acc, 32);
    float v = fmaxf(acc * dn + bias[c], 0.f);   // all lanes hold full sum; full exec
    if (lane < 16) x3o[node * HID + c] = v;
    int gbase = lane & 48;
    float hacc = 0.f;
    #pragma unroll
    for (int cc = 0; cc < 16; cc++)
        hacc += __shfl(v, gbase | cc) * W3[cc * HID + c];
    if (lane < 16) h3o[node * HID + c] = (f16)hacc;
}

// GAT aggregate, 3 WAVES per node (192-thread block, block-per-node).
// Lane owns channel c = w*64+lane, head c>>4. Each 16-lane head group redundantly
// computes identical (m,s) from identical inputs -> ZERO per-edge shuffles, fully
// lane-local online softmax with defer-max. 75000 waves of TLP. Fused GEMM2 via LDS.
__global__ void k_gat3(const f16* __restrict__ hg, const float* __restrict__ a_s,
                       const float* __restrict__ a_d, const int* __restrict__ rowstart,
                       const int* __restrict__ csr, const float* __restrict__ bg,
                       const float* __restrict__ W2, f16* __restrict__ h2, int n) {
    __shared__ float sx2[HF];
    __shared__ float sp[3][16];
    int node = blockIdx.x;
    int t = threadIdx.x;                     // 0..191
    int w = t >> 6;                          // wave slot 0..2
    int lane = t & 63;
    int c = t;                               // channel = w*64+lane
    int h = c >> 4;                          // head 0..11
    int base = rowstart[node], deg = rowstart[node + 1] - base;
    int dcap = deg < 64 ? deg : 64;
    int eidx = (lane < dcap) ? csr[base + lane] : 0;   // per-wave replica

    float ad = a_d[node * HEADS + h];
    float e0 = a_s[node * HEADS + h] + ad;   // self loop
    e0 = fmaxf(e0, 0.2f * e0);               // leaky_relu
    float m = e0, s = 1.f;
    float acc = (float)hg[(size_t)node * HF + c];      // p=1 rel. to m

#define EDGE(A, G)                                         \
    {                                                      \
        float e = (A) + ad;                                \
        e = fmaxf(e, 0.2f * e);                            \
        float d = e - m;                                   \
        float p = __expf(d);                               \
        if (__any(d > 8.f)) {          /* rare rescale */  \
            bool big = d > 8.f;                            \
            float rp = big ? __expf(-d) : 1.f;             \
            float pe = big ? 1.f : p;                      \
            s = s * rp + pe;                               \
            if (big) m = e;                                \
            acc = acc * rp + pe * (G);                     \
        } else {                                           \
            s += p;                                        \
            acc += p * (G);                                \
        }                                                  \
    }

    int j = 0;
    for (; j + 4 <= dcap; j += 4) {          // wave-uniform; 8 gathers in flight
        int s0 = __shfl(eidx, j),     s1 = __shfl(eidx, j + 1);
        int s2 = __shfl(eidx, j + 2), s3 = __shfl(eidx, j + 3);
        float A0 = a_s[s0 * HEADS + h], A1 = a_s[s1 * HEADS + h];
        float A2 = a_s[s2 * HEADS + h], A3 = a_s[s3 * HEADS + h];
        float g0 = (float)hg[(size_t)s0 * HF + c];
        float g1 = (float)hg[(size_t)s1 * HF + c];
        float g2 = (float)hg[(size_t)s2 * HF + c];
        float g3 = (float)hg[(size_t)s3 * HF + c];
        EDGE(A0, g0)
        EDGE(A1, g1)
        EDGE(A2, g2)
        EDGE(A3, g3)
    }
    for (; j < dcap; j++) {                  // tail, wave-uniform j
        int s0 = __shfl(eidx, j);
        float A0 = a_s[s0 * HEADS + h];
        float g0 = (float)hg[(size_t)s0 * HF + c];
        EDGE(A0, g0)
    }
    for (; j < deg; j++) {                   // deg>64 fallback (≈never)
        int s0 = csr[base + j];
        float A0 = a_s[s0 * HEADS + h];
        float g0 = (float)hg[(size_t)s0 * HF + c];
        EDGE(A0, g0)
    }
#undef EDGE

    float v = acc / s + bg[c];
    v = (v > 0.f) ? v : (__expf(v) - 1.f);   // elu -> x2 (LDS only, never global)
    sx2[c] = v;
    __syncthreads();
    // fused GEMM2: each wave computes partial over its own 64 channels
    if (lane < 16) {
        float a = 0.f;
        #pragma unroll 16
        for (int k = 0; k < 64; k++)
            a += sx2[w * 64 + k] * W2[(w * 64 + k) * HID + lane];
        sp[w][lane] = a;
    }
    __syncthreads();
    if (t < 16) h2[node * HID + t] = (f16)(sp[0][t] + sp[1][t] + sp[2][t]);
}

// ---------------- Fused mean + final linear (last-block pattern) ----------------

__global__ void k_mean_final(const float* __restrict__ x4, float* __restrict__ red,
                             int* __restrict__ done, const float* __restrict__ Wlin,
                             const float* __restrict__ blin, float* __restrict__ out,
                             float invN, int n, int nblocks) {
    __shared__ float sd[16][17];
    __shared__ float sred[16];
    __shared__ int slast;
    int t = threadIdx.x;
    int ln = t >> 4, c = t & 15;
    float acc = 0.f;
    for (int node = blockIdx.x * 16 + ln; node < n; node += gridDim.x * 16)
        acc += x4[node * HID + c];
    sd[ln][c] = acc;
    __syncthreads();
    for (int off = 8; off >= 1; off >>= 1) {
        if (ln < off) sd[ln][c] += sd[ln + off][c];
        __syncthreads();
    }
    if (ln == 0) atomicAdd(&red[c], sd[0][c]);
    __threadfence();
    __syncthreads();
    if (t == 0) slast = (atomicAdd(done, 1) == nblocks - 1);
    __syncthreads();
    if (slast) {
        if (t < 16) sred[t] = atomicAdd(&red[t], 0.0f);   // coherent read via atomic
        __syncthreads();
        if (t < OUT_C) {
            float a = blin[t];
            #pragma unroll
            for (int cc = 0; cc < HID; cc++) a += (sred[cc] * invN) * Wlin[cc * OUT_C + t];
            out[t] = a;
        }
    }
}

// ---------------- launch ----------------

extern "C" void kernel_launch(void* const* d_in, const int* in_sizes, int n_in,
                              void* d_out, int out_size, void* d_ws, size_t ws_size,
                              hipStream_t stream) {
    const float* x     = (const float*)d_in[0];
    const void*  ei    = d_in[1];
    const float* W1    = (const float*)d_in[2];
    const float* b1    = (const float*)d_in[3];
    const float* Wg    = (const float*)d_in[4];
    const float* att_s = (const float*)d_in[5];
    const float* att_d = (const float*)d_in[6];
    const float* bg    = (const float*)d_in[7];
    const float* W2    = (const float*)d_in[8];
    const float* b2    = (const float*)d_in[9];
    const float* W3    = (const float*)d_in[10];
    const float* b3    = (const float*)d_in[11];
    const float* Wlin  = (const float*)d_in[12];
    const float* blin  = (const float*)d_in[13];
    float* out = (float*)d_out;

    int N = in_sizes[0] / F_IN;
    int E = in_sizes[1] / 2;

    char* w = (char*)d_ws;
    size_t off = 0;
    auto alloc = [&](size_t bytes) -> void* {
        void* p = w + off;
        off += (bytes + 255) & ~(size_t)255;
        return p;
    };
    // contiguous zero region: count | cursor | red+done  (one memset)
    int*   count    = (int*)alloc((size_t)N * 4);
    int*   cursor   = (int*)alloc((size_t)N * 4);
    float* red      = (float*)alloc(256);          // red[16] + done
    int*   done     = (int*)((char*)red + 64);
    size_t zbytes   = (size_t)((char*)red + 256 - (char*)count);
    int*   src32    = (int*)alloc((size_t)E * 4);
    int*   dst32    = (int*)alloc((size_t)E * 4);
    int*   rowstart = (int*)alloc((size_t)(N + 1) * 4);
    int*   csr      = (int*)alloc((size_t)E * 4);
    float* dinv     = (float*)alloc((size_t)N * 4);
    f16*   h1       = (f16*)alloc((size_t)N * HID * 2);
    float* x1       = (float*)alloc((size_t)N * HID * 4);
    f16*   hg       = (f16*)alloc((size_t)N * HF * 2);
    float* a_s      = (float*)alloc((size_t)N * HEADS * 4);
    float* a_d      = (float*)alloc((size_t)N * HEADS * 4);
    f16*   h2       = (f16*)alloc((size_t)N * HID * 2);
    float* x3       = (float*)alloc((size_t)N * HID * 4);
    f16*   h3       = (f16*)alloc((size_t)N * HID * 2);
    float* x4       = (float*)alloc((size_t)N * HID * 4);
    if (off > ws_size) return;

    hipMemsetAsync(count, 0, zbytes, stream);    // zeros count+cursor+red+done

    int eb = (E + 255) / 256;
    int nb16 = (N + 15) / 16;
    int nbw  = (N + 3) / 4;      // one wave per node, 256-thread blocks

    k_convert<<<eb, 256, 0, stream>>>(ei, E, src32, dst32, count);
    k_scan<<<1, 1024, 0, stream>>>(count, rowstart, dinv, N);
    k_fill_gemm1<<<eb + nb16, 256, 0, stream>>>(src32, dst32, E, rowstart, cursor, csr,
                                                x, W1, h1, N, eb);

    k_gcn_agg<<<nbw, 256, 0, stream>>>(h1, rowstart, csr, dinv, b1, nullptr, x1, N);

    k_gemm_gat<<<2048, 192, 0, stream>>>(x1, Wg, att_s, att_d, hg, a_s, a_d, N);
    k_gat3<<<N, 192, 0, stream>>>(hg, a_s, a_d, rowstart, csr, bg, W2, h2, N);

    k_gcn_agg_f3<<<nbw, 256, 0, stream>>>(h2, rowstart, csr, dinv, b2, W3, x3, h3, N);
    k_gcn_agg<<<nbw, 256, 0, stream>>>(h3, rowstart, csr, dinv, b3, x3, x4, N);

    k_mean_final<<<128, 256, 0, stream>>>(x4, red, done, Wlin, blin, out,
                                          1.0f / (float)N, N, 128);
}